// Round 1
// baseline (1014.255 us; speedup 1.0000x reference)
//
#include <hip/hip_runtime.h>

#define H_ 128
#define T_ 1024
#define B_ 512
#define I_ 13
#define LOG2E 1.4426950408889634f

typedef _Float16 half8 __attribute__((ext_vector_type(8)));
typedef float float4_ __attribute__((ext_vector_type(4)));

static __device__ __forceinline__ float fast_rcp(float v) {
#if __has_builtin(__builtin_amdgcn_rcpf)
  return __builtin_amdgcn_rcpf(v);
#else
  return 1.0f / v;
#endif
}
static __device__ __forceinline__ float fast_exp2(float v) {
#if __has_builtin(__builtin_amdgcn_exp2f)
  return __builtin_amdgcn_exp2f(v);
#else
  return exp2f(v);
#endif
}
static __device__ __forceinline__ float sigmoid_f(float v) {
  return fast_rcp(1.0f + fast_exp2(-LOG2E * v));
}
static __device__ __forceinline__ float tanh_f(float v) {
  return 2.0f * fast_rcp(1.0f + fast_exp2(-2.0f * LOG2E * v)) - 1.0f;
}

// One WG per CU (256 WGs), each owns 2 batch rows for the whole sequence.
// W_hh/W_ih/W_fc live in per-wave VGPR MFMA B-fragments (loop-invariant).
// Per step: 33 col-tiles (32 gate tiles + 1 fc tile) x 5 K-chunks of
// mfma_f32_16x16x32_f16 with A = [h | x] (rows 0..1 real, 2..15 zero).
__global__ __launch_bounds__(512, 2) void lstm_fused(
    const float* __restrict__ x, const float* __restrict__ Wih,
    const float* __restrict__ Whh, const float* __restrict__ bih,
    const float* __restrict__ bhh, const float* __restrict__ Wfc,
    const float* __restrict__ bfc, float* __restrict__ out)
{
  // A-buffer: 2 rows x 168 f16 (cols 0..127 h, 128..140 x, rest zero pad).
  // Row stride 168 halfs = 336 B = 21*16 -> 16B-aligned frag loads, and
  // 84-dword stride gives 2-way-max bank aliasing (free).
  __shared__ __align__(16) _Float16 abuf[2][168];
  // gates, col-major: glds[c*2 + row], cols 0..511 gates, 512..518 logits
  __shared__ __align__(16) float glds[528 * 2];

  const int tid  = threadIdx.x;
  const int wave = tid >> 6;
  const int lane = tid & 63;
  const int n16  = lane & 15;   // MFMA B col / A row / D col index
  const int quad = lane >> 4;
  const int wgb  = blockIdx.x * 2;

  // ---- W fragments: wave w owns gate tiles {w, w+8, w+16, w+24} ----
  // B layout (16x16x32): lane holds B[k = quad*8 + j][n = n16], j=0..7
  half8 wfrag[4][5];
  float biasv[4];
  #pragma unroll
  for (int ti = 0; ti < 4; ++ti) {
    const int tile = wave + 8 * ti;
    const int col  = tile * 16 + n16;        // gate index 0..511
    biasv[ti] = bih[col] + bhh[col];
    #pragma unroll
    for (int kc = 0; kc < 5; ++kc) {
      half8 f;
      #pragma unroll
      for (int j = 0; j < 8; ++j) {
        const int k = kc * 32 + quad * 8 + j;
        float v = 0.0f;
        if (k < 128)            v = Whh[col * H_ + k];
        else if (k < 128 + I_)  v = Wih[col * I_ + (k - 128)];
        f[j] = (_Float16)v;
      }
      wfrag[ti][kc] = f;
    }
  }
  // fc tile (tile 32): used by wave 0 only (loaded by all, uniform code)
  half8 wfc[5];
  float biasfc = (n16 < 7) ? bfc[n16] : 0.0f;
  #pragma unroll
  for (int kc = 0; kc < 5; ++kc) {
    half8 f;
    #pragma unroll
    for (int j = 0; j < 8; ++j) {
      const int k = kc * 32 + quad * 8 + j;
      float v = 0.0f;
      if (n16 < 7 && k < 128) v = Wfc[n16 * H_ + k];
      f[j] = (_Float16)v;
    }
    wfc[kc] = f;
  }

  // ---- init LDS: zero A-buffer, then write x(0) ----
  for (int i2 = tid; i2 < 2 * 168; i2 += 512)
    ((_Float16*)abuf)[i2] = (_Float16)0.0f;
  __syncthreads();
  if (tid < 26) {
    const int b = tid / 13, ii = tid - 13 * (tid / 13);
    abuf[b][128 + ii] = (_Float16)x[(size_t)(wgb + b) * I_ + ii];
  }
  __syncthreads();

  float c_state = 0.0f;                 // threads 0..255: cell (tid&1, tid>>1)
  const int ub = tid & 1, uj = tid >> 1;

  // A fragments: zero once; only lanes with n16<2 ever (re)load -> rows 2..15
  // of the A tile stay zero in registers forever.
  half8 af[5];
  {
    half8 z;
    #pragma unroll
    for (int j = 0; j < 8; ++j) z[j] = (_Float16)0.0f;
    #pragma unroll
    for (int kc = 0; kc < 5; ++kc) af[kc] = z;
  }

  for (int t = 0; t <= T_; ++t) {
    // prefetch x(t+1) early so global latency hides under the MFMA phase
    float xnext = 0.0f;
    if (wave == 4 && lane < 26 && (t + 1) < T_) {
      const int b = lane / 13, ii = lane - 13 * (lane / 13);
      xnext = x[((size_t)(t + 1) * B_ + wgb + b) * I_ + ii];
    }

    // ---- phase 1: gates = [h|x] @ [Whh|Wih]^T + bias, plus fc logits ----
    if (n16 < 2) {
      #pragma unroll
      for (int kc = 0; kc < 5; ++kc)
        af[kc] = *(const half8*)&abuf[n16][kc * 32 + quad * 8];
    }
    float4_ acc[4];
    #pragma unroll
    for (int ti = 0; ti < 4; ++ti) {
      #pragma unroll
      for (int r = 0; r < 4; ++r) acc[ti][r] = biasv[ti];
    }
    float4_ accf;
    #pragma unroll
    for (int r = 0; r < 4; ++r) accf[r] = biasfc;

    #pragma unroll
    for (int kc = 0; kc < 5; ++kc) {
      #pragma unroll
      for (int ti = 0; ti < 4; ++ti)
        acc[ti] = __builtin_amdgcn_mfma_f32_16x16x32_f16(af[kc], wfrag[ti][kc], acc[ti], 0, 0, 0);
      if (wave == 0)
        accf = __builtin_amdgcn_mfma_f32_16x16x32_f16(af[kc], wfc[kc], accf, 0, 0, 0);
    }
    // D layout: col = lane&15, row = quad*4 + reg -> rows 0,1 are regs 0,1 of
    // lanes 0..15
    if (lane < 16) {
      #pragma unroll
      for (int ti = 0; ti < 4; ++ti) {
        const int col = (wave + 8 * ti) * 16 + lane;
        *(float2*)&glds[col * 2] = make_float2(acc[ti][0], acc[ti][1]);
      }
      if (wave == 0)
        *(float2*)&glds[(512 + lane) * 2] = make_float2(accf[0], accf[1]);
    }
    __syncthreads();

    // ---- phase 2: cell update (waves 0-3), x write (wave 4), softmax (5) --
    if (t < T_ && tid < 256) {
      const float gi = glds[(uj) * 2 + ub];
      const float gf = glds[(128 + uj) * 2 + ub];
      const float gg = glds[(256 + uj) * 2 + ub];
      const float go = glds[(384 + uj) * 2 + ub];
      const float iv = sigmoid_f(gi);
      const float fv = sigmoid_f(gf);
      const float gv = tanh_f(gg);
      const float ov = sigmoid_f(go);
      c_state = fv * c_state + iv * gv;
      const float hv = ov * tanh_f(c_state);
      abuf[ub][uj] = (_Float16)hv;
    }
    if (wave == 4 && lane < 26 && (t + 1) < T_) {
      const int b = lane / 13, ii = lane - 13 * (lane / 13);
      abuf[b][128 + ii] = (_Float16)xnext;
    }
    if (t >= 1 && wave == 5 && lane < 14) {
      // logits in glds cols 512..518 came from h(t-1) -> output row t-1
      const int b = lane / 7, kk = lane - 7 * (lane / 7);
      float mx = -3.0e38f;
      #pragma unroll
      for (int k2 = 0; k2 < 7; ++k2)
        mx = fmaxf(mx, glds[(512 + k2) * 2 + b]);
      float s = 0.0f;
      #pragma unroll
      for (int k2 = 0; k2 < 7; ++k2)
        s += fast_exp2(LOG2E * (glds[(512 + k2) * 2 + b] - mx));
      const float p = fast_exp2(LOG2E * (glds[(512 + kk) * 2 + b] - mx)) * fast_rcp(s);
      out[((size_t)(t - 1) * B_ + wgb + b) * 7 + kk] = p;
    }
    __syncthreads();
  }
}

extern "C" void kernel_launch(void* const* d_in, const int* in_sizes, int n_in,
                              void* d_out, int out_size, void* d_ws, size_t ws_size,
                              hipStream_t stream) {
  (void)in_sizes; (void)n_in; (void)out_size; (void)d_ws; (void)ws_size;
  const float* x   = (const float*)d_in[0];
  const float* Wih = (const float*)d_in[1];
  const float* Whh = (const float*)d_in[2];
  const float* bih = (const float*)d_in[3];
  const float* bhh = (const float*)d_in[4];
  const float* Wfc = (const float*)d_in[5];
  const float* bfc = (const float*)d_in[6];
  hipLaunchKernelGGL(lstm_fused, dim3(256), dim3(512), 0, stream,
                     x, Wih, Whh, bih, bhh, Wfc, bfc, (float*)d_out);
}